// Round 2
// baseline (665.846 us; speedup 1.0000x reference)
//
#include <hip/hip_runtime.h>

// ---------------------------------------------------------------------------
// GNNWithPrompt, f32 I/O. Split-bf16 (hi+lo) MFMA GEMMs for f32-level
// precision at matrix-core rate. CSR mean aggregation (no f32 atomics).
// Layer-0 input h=[features|sel] is never materialized: gather reads
// features + compact p_sel directly.
// ---------------------------------------------------------------------------

#define N0v 200000
#define N1v 50000
#define N2v 10000
#define E0v 800000
#define E1v 160000

using u16 = unsigned short;
typedef __attribute__((ext_vector_type(8))) short short8;
typedef __attribute__((ext_vector_type(4))) float f32x4;

__device__ __forceinline__ float b2f(u16 u) {
    union { unsigned int i; float f; } v; v.i = ((unsigned int)u) << 16; return v.f;
}
__device__ __forceinline__ u16 f2b(float f) {  // round-to-nearest-even
    union { float f; unsigned int i; } v; v.f = f;
    unsigned int r = (v.i + 0x7fffu + ((v.i >> 16) & 1u)) >> 16;
    return (u16)r;
}
__device__ __forceinline__ void split2(float f, u16& hi, u16& lo) {
    hi = f2b(f);
    lo = f2b(f - b2f(hi));
}

// --- mask storage detection: flag=1 if packed bytes, 0 if int32 ------------
__global__ void k_detect(const unsigned int* m, int nwords, int* flag) {
    int found = 0;
    for (int i = blockIdx.x * blockDim.x + threadIdx.x; i < nwords;
         i += gridDim.x * blockDim.x)
        if (m[i] > 1u) found = 1;
    if (found) atomicOr(flag, 1);
}

// --- weight prep: WT = vstack(Wa[Ka,N], Wb[K-Ka,N])^T, split hi/lo ---------
__global__ void k_wsplit_vcat(const float* Wa, const float* Wb, u16* WTh, u16* WTl,
                              int Ka, int K, int N) {
    int total = N * K;
    for (int i = blockIdx.x * blockDim.x + threadIdx.x; i < total;
         i += gridDim.x * blockDim.x) {
        int n = i / K, k = i % K;
        float f = (k < Ka) ? Wa[k * N + n] : Wb[(k - Ka) * N + n];
        split2(f, WTh[i], WTl[i]);
    }
}
// WT = hstack(Wa[K,Nh], Wb[K,Nh])^T, split hi/lo
__global__ void k_wsplit_hcat(const float* Wa, const float* Wb, u16* WTh, u16* WTl,
                              int K, int Nh) {
    int N = 2 * Nh, total = N * K;
    for (int i = blockIdx.x * blockDim.x + threadIdx.x; i < total;
         i += gridDim.x * blockDim.x) {
        int n = i / K, k = i % K;
        float f = (n < Nh) ? Wa[k * Nh + n] : Wb[k * Nh + (n - Nh)];
        split2(f, WTh[i], WTl[i]);
    }
}

// --- MFMA GEMM core macro-ish pieces ---------------------------------------
// C[M,N] = act(A[M,K](f32) @ BT[N,K]^T + bias), 64x64 tile, 4 waves, split-bf16.
// K % 32 == 0, N % 64 == 0.
template <bool RELU>
__global__ __launch_bounds__(256) void k_gemm(const float* __restrict__ A,
                                              const u16* __restrict__ BTh,
                                              const u16* __restrict__ BTl,
                                              const float* __restrict__ bias,
                                              float* __restrict__ C,
                                              int M, int K, int N) {
    __shared__ __align__(16) u16 lah[64 * 40];
    __shared__ __align__(16) u16 lal[64 * 40];
    __shared__ __align__(16) u16 lbh[64 * 40];
    __shared__ __align__(16) u16 lbl[64 * 40];
    const int t = threadIdx.x;
    const int bm = blockIdx.x, bn = blockIdx.y;
    const int lane = t & 63, w = t >> 6;
    const int m = lane & 15, q = lane >> 4;
    const int lr = t >> 2;       // staging row 0..63
    const int lc = (t & 3) * 8;  // staging col group {0,8,16,24}
    int arow = bm * 64 + lr;
    const int ar = (arow < M) ? arow : (M - 1);
    const int brow = bn * 64 + lr;
    f32x4 acc[4] = {};

    for (int k0 = 0; k0 < K; k0 += 32) {
        const float* ap = &A[(size_t)ar * K + k0 + lc];
        float4 av0 = *(const float4*)(ap);
        float4 av1 = *(const float4*)(ap + 4);
        u16 h8[8], l8[8];
        split2(av0.x, h8[0], l8[0]); split2(av0.y, h8[1], l8[1]);
        split2(av0.z, h8[2], l8[2]); split2(av0.w, h8[3], l8[3]);
        split2(av1.x, h8[4], l8[4]); split2(av1.y, h8[5], l8[5]);
        split2(av1.z, h8[6], l8[6]); split2(av1.w, h8[7], l8[7]);
        *(uint4*)(&lah[lr * 40 + lc]) = *(const uint4*)h8;
        *(uint4*)(&lal[lr * 40 + lc]) = *(const uint4*)l8;
        *(uint4*)(&lbh[lr * 40 + lc]) = *(const uint4*)(&BTh[(size_t)brow * K + k0 + lc]);
        *(uint4*)(&lbl[lr * 40 + lc]) = *(const uint4*)(&BTl[(size_t)brow * K + k0 + lc]);
        __syncthreads();
        short8 avh = *(const short8*)(&lah[(w * 16 + m) * 40 + q * 8]);
        short8 avl = *(const short8*)(&lal[(w * 16 + m) * 40 + q * 8]);
#pragma unroll
        for (int nt = 0; nt < 4; nt++) {
            short8 bvh = *(const short8*)(&lbh[(nt * 16 + m) * 40 + q * 8]);
            short8 bvl = *(const short8*)(&lbl[(nt * 16 + m) * 40 + q * 8]);
            acc[nt] = __builtin_amdgcn_mfma_f32_16x16x32_bf16(avh, bvh, acc[nt], 0, 0, 0);
            acc[nt] = __builtin_amdgcn_mfma_f32_16x16x32_bf16(avh, bvl, acc[nt], 0, 0, 0);
            acc[nt] = __builtin_amdgcn_mfma_f32_16x16x32_bf16(avl, bvh, acc[nt], 0, 0, 0);
        }
        __syncthreads();
    }
#pragma unroll
    for (int nt = 0; nt < 4; nt++) {
        int col = bn * 64 + nt * 16 + m;
        float bv = bias[col];
#pragma unroll
        for (int r = 0; r < 4; r++) {
            int row = bm * 64 + w * 16 + q * 4 + r;
            if (row < M) {
                float v = acc[nt][r] + bv;
                if (RELU) v = v > 0.f ? v : 0.f;
                C[(size_t)row * N + col] = v;
            }
        }
    }
}

// --- prompt GEMM, fused select: writes p_sel[N0,64] ------------------------
// N=128 (bn 0 -> p_in cols, bn 1 -> p_out cols); row selected by mask.
__global__ __launch_bounds__(256) void k_gemm_p(const float* __restrict__ A,
                                                const u16* __restrict__ BTh,
                                                const u16* __restrict__ BTl,
                                                const float* __restrict__ b_pin,
                                                const float* __restrict__ b_pout,
                                                const void* maskp,
                                                const int* __restrict__ flag,
                                                float* __restrict__ p_sel) {
    const int K = 128;
    __shared__ __align__(16) u16 lah[64 * 40];
    __shared__ __align__(16) u16 lal[64 * 40];
    __shared__ __align__(16) u16 lbh[64 * 40];
    __shared__ __align__(16) u16 lbl[64 * 40];
    const int t = threadIdx.x;
    const int bm = blockIdx.x, bn = blockIdx.y;
    const int lane = t & 63, w = t >> 6;
    const int m = lane & 15, q = lane >> 4;
    const int lr = t >> 2;
    const int lc = (t & 3) * 8;
    const int ar = bm * 64 + lr;       // M=200000 = 3125*64, always in range
    const int brow = bn * 64 + lr;
    const int fl = *flag;
    f32x4 acc[4] = {};

    for (int k0 = 0; k0 < K; k0 += 32) {
        const float* ap = &A[(size_t)ar * K + k0 + lc];
        float4 av0 = *(const float4*)(ap);
        float4 av1 = *(const float4*)(ap + 4);
        u16 h8[8], l8[8];
        split2(av0.x, h8[0], l8[0]); split2(av0.y, h8[1], l8[1]);
        split2(av0.z, h8[2], l8[2]); split2(av0.w, h8[3], l8[3]);
        split2(av1.x, h8[4], l8[4]); split2(av1.y, h8[5], l8[5]);
        split2(av1.z, h8[6], l8[6]); split2(av1.w, h8[7], l8[7]);
        *(uint4*)(&lah[lr * 40 + lc]) = *(const uint4*)h8;
        *(uint4*)(&lal[lr * 40 + lc]) = *(const uint4*)l8;
        *(uint4*)(&lbh[lr * 40 + lc]) = *(const uint4*)(&BTh[(size_t)brow * K + k0 + lc]);
        *(uint4*)(&lbl[lr * 40 + lc]) = *(const uint4*)(&BTl[(size_t)brow * K + k0 + lc]);
        __syncthreads();
        short8 avh = *(const short8*)(&lah[(w * 16 + m) * 40 + q * 8]);
        short8 avl = *(const short8*)(&lal[(w * 16 + m) * 40 + q * 8]);
#pragma unroll
        for (int nt = 0; nt < 4; nt++) {
            short8 bvh = *(const short8*)(&lbh[(nt * 16 + m) * 40 + q * 8]);
            short8 bvl = *(const short8*)(&lbl[(nt * 16 + m) * 40 + q * 8]);
            acc[nt] = __builtin_amdgcn_mfma_f32_16x16x32_bf16(avh, bvh, acc[nt], 0, 0, 0);
            acc[nt] = __builtin_amdgcn_mfma_f32_16x16x32_bf16(avh, bvl, acc[nt], 0, 0, 0);
            acc[nt] = __builtin_amdgcn_mfma_f32_16x16x32_bf16(avl, bvh, acc[nt], 0, 0, 0);
        }
        __syncthreads();
    }
#pragma unroll
    for (int nt = 0; nt < 4; nt++) {
        int colw = bn * 64 + nt * 16 + m;  // 0..127 within [p_in|p_out]
        float bv = (colw < 64) ? b_pin[colw] : b_pout[colw - 64];
#pragma unroll
        for (int r = 0; r < 4; r++) {
            int row = bm * 64 + w * 16 + q * 4 + r;
            bool mk = fl ? (((const unsigned char*)maskp)[row] != 0)
                         : (((const int*)maskp)[row] != 0);
            if (mk == (bn == 0)) {
                float v = acc[nt][r] + bv;
                p_sel[(size_t)row * 64 + (colw & 63)] = v > 0.f ? v : 0.f;
            }
        }
    }
}

// --- CSR build -------------------------------------------------------------
__global__ void k_count(const int* __restrict__ dst, int E, int* cnt) {
    for (int i = blockIdx.x * blockDim.x + threadIdx.x; i < E;
         i += gridDim.x * blockDim.x)
        atomicAdd(&cnt[dst[i]], 1);
}

__global__ __launch_bounds__(1024) void k_scan(const int* __restrict__ cnt,
                                               int* __restrict__ off, int n) {
    __shared__ int lds[1024];
    int t = threadIdx.x;
    int chunk = (n + 1023) >> 10;
    int b = t * chunk, e = b + chunk;
    if (e > n) e = n;
    int s = 0;
    for (int i = b; i < e; i++) s += cnt[i];
    lds[t] = s;
    __syncthreads();
    for (int d = 1; d < 1024; d <<= 1) {
        int v = (t >= d) ? lds[t - d] : 0;
        __syncthreads();
        lds[t] += v;
        __syncthreads();
    }
    int run = lds[t] - s;  // exclusive prefix
    for (int i = b; i < e; i++) { off[i] = run; run += cnt[i]; }
    if (t == 1023) off[n] = lds[1023];
}

__global__ void k_scatter(const int* __restrict__ src, const int* __restrict__ dst,
                          int E, const int* __restrict__ off, int* cur,
                          int* __restrict__ eidx) {
    for (int i = blockIdx.x * blockDim.x + threadIdx.x; i < E;
         i += gridDim.x * blockDim.x) {
        int d = dst[i];
        int p = off[d] + atomicAdd(&cur[d], 1);
        eidx[p] = src[i];
    }
}

// --- layer-0 aggregate: wave per dst; h=[feat(128)|p_sel(64)] virtual ------
__global__ void k_agg0(const float* __restrict__ feat, const float* __restrict__ psel,
                       const int* __restrict__ off, const int* __restrict__ eidx,
                       float* __restrict__ hcat) {
    int wid = (blockIdx.x * blockDim.x + threadIdx.x) >> 6;
    int lane = threadIdx.x & 63;
    if (wid >= N1v) return;
    int b = off[wid], e = off[wid + 1];
    float f0 = 0.f, f1 = 0.f, ps = 0.f;
    for (int i = b; i < e; i++) {
        int s = eidx[i];
        f0 += feat[(size_t)s * 128 + lane];
        f1 += feat[(size_t)s * 128 + 64 + lane];
        ps += psel[(size_t)s * 64 + lane];
    }
    int deg = e - b;
    float inv = 1.0f / (float)(deg > 1 ? deg : 1);
    size_t ob = (size_t)wid * 384;
    hcat[ob + lane]       = feat[(size_t)wid * 128 + lane];
    hcat[ob + 64 + lane]  = feat[(size_t)wid * 128 + 64 + lane];
    hcat[ob + 128 + lane] = psel[(size_t)wid * 64 + lane];
    hcat[ob + 192 + lane] = f0 * inv;
    hcat[ob + 256 + lane] = f1 * inv;
    hcat[ob + 320 + lane] = ps * inv;
}

// --- layer-1 aggregate: wave per dst, 256 f32 ------------------------------
__global__ void k_agg1(const float* __restrict__ h1, const int* __restrict__ off,
                       const int* __restrict__ eidx, float* __restrict__ hcat) {
    int wid = (blockIdx.x * blockDim.x + threadIdx.x) >> 6;
    int lane = threadIdx.x & 63;
    if (wid >= N2v) return;
    int b = off[wid], e = off[wid + 1];
    float a[4] = {0.f, 0.f, 0.f, 0.f};
    for (int i = b; i < e; i++) {
        size_t base = (size_t)eidx[i] * 256 + lane;
#pragma unroll
        for (int j = 0; j < 4; j++) a[j] += h1[base + 64 * j];
    }
    int deg = e - b;
    float inv = 1.0f / (float)(deg > 1 ? deg : 1);
    size_t ob = (size_t)wid * 512;
    size_t sb = (size_t)wid * 256;
#pragma unroll
    for (int j = 0; j < 4; j++) {
        hcat[ob + 64 * j + lane] = h1[sb + 64 * j + lane];
        hcat[ob + 256 + 64 * j + lane] = a[j] * inv;
    }
}

// --- classifier: wave per row, [10000,256] x [256,2] + b -------------------
__global__ void k_cls(const float* __restrict__ h2, const float* __restrict__ wc,
                      const float* __restrict__ bc, float* __restrict__ out) {
    int wid = (blockIdx.x * blockDim.x + threadIdx.x) >> 6;
    int lane = threadIdx.x & 63;
    if (wid >= N2v) return;
    float a0 = 0.f, a1 = 0.f;
#pragma unroll
    for (int j = 0; j < 4; j++) {
        int k = lane + 64 * j;
        float hv = h2[(size_t)wid * 256 + k];
        a0 += hv * wc[k * 2];
        a1 += hv * wc[k * 2 + 1];
    }
    for (int s = 32; s; s >>= 1) {
        a0 += __shfl_down(a0, s);
        a1 += __shfl_down(a1, s);
    }
    if (lane == 0) {
        out[wid * 2] = a0 + bc[0];
        out[wid * 2 + 1] = a1 + bc[1];
    }
}

extern "C" void kernel_launch(void* const* d_in, const int* in_sizes, int n_in,
                              void* d_out, int out_size, void* d_ws, size_t ws_size,
                              hipStream_t stream) {
    const float* features = (const float*)d_in[0];
    const void* maskp     = d_in[1];
    const int* src0       = (const int*)d_in[2];
    const int* dst0       = (const int*)d_in[3];
    const int* src1       = (const int*)d_in[4];
    const int* dst1       = (const int*)d_in[5];
    // d_in[6] output_nodes_indices: unused by reference
    const float* w_pin    = (const float*)d_in[7];
    const float* b_pin    = (const float*)d_in[8];
    const float* w_pout   = (const float*)d_in[9];
    const float* b_pout   = (const float*)d_in[10];
    const float* w_self0  = (const float*)d_in[11];
    const float* w_neigh0 = (const float*)d_in[12];
    const float* b0       = (const float*)d_in[13];
    const float* w_self1  = (const float*)d_in[14];
    const float* w_neigh1 = (const float*)d_in[15];
    const float* b1       = (const float*)d_in[16];
    const float* w_cls    = (const float*)d_in[17];
    const float* b_cls    = (const float*)d_in[18];
    float* out = (float*)d_out;
    (void)in_sizes; (void)n_in; (void)out_size; (void)ws_size;

    // ---- workspace layout (256B aligned) ----
    char* ws = (char*)d_ws;
    size_t o = 0;
    auto alloc = [&](size_t bytes) { size_t r = o; o += (bytes + 255) & ~(size_t)255; return r; };
    size_t o_flag  = alloc(4);
    size_t o_psel  = alloc((size_t)N0v * 64 * 4);     // 51.2 MB; later hcat1 + h2
    size_t o_hcat0 = alloc((size_t)N1v * 384 * 4);    // 76.8 MB
    size_t o_h1    = alloc((size_t)N1v * 256 * 4);    // 51.2 MB
    size_t o_wtph  = alloc(128 * 128 * 2);
    size_t o_wtpl  = alloc(128 * 128 * 2);
    size_t o_wt0h  = alloc(256 * 384 * 2);
    size_t o_wt0l  = alloc(256 * 384 * 2);
    size_t o_wt1h  = alloc(256 * 512 * 2);
    size_t o_wt1l  = alloc(256 * 512 * 2);
    size_t o_cnt0  = alloc(N1v * 4);
    size_t o_cur0  = alloc(N1v * 4);
    size_t o_off0  = alloc((N1v + 1) * 4);
    size_t o_cnt1  = alloc(N2v * 4);
    size_t o_cur1  = alloc(N2v * 4);
    size_t o_off1  = alloc((N2v + 1) * 4);
    size_t o_ei0   = alloc((size_t)E0v * 4);
    size_t o_ei1   = alloc((size_t)E1v * 4);

    int* flag    = (int*)(ws + o_flag);
    float* psel  = (float*)(ws + o_psel);
    float* hcat1 = (float*)(ws + o_psel);                       // alias: psel dead after agg0
    float* h2    = (float*)(ws + o_psel + (size_t)N2v * 512 * 4);
    float* hcat0 = (float*)(ws + o_hcat0);
    float* h1    = (float*)(ws + o_h1);
    u16* WTph = (u16*)(ws + o_wtph);
    u16* WTpl = (u16*)(ws + o_wtpl);
    u16* WT0h = (u16*)(ws + o_wt0h);
    u16* WT0l = (u16*)(ws + o_wt0l);
    u16* WT1h = (u16*)(ws + o_wt1h);
    u16* WT1l = (u16*)(ws + o_wt1l);
    int* cnt0 = (int*)(ws + o_cnt0);
    int* cur0 = (int*)(ws + o_cur0);
    int* off0 = (int*)(ws + o_off0);
    int* cnt1 = (int*)(ws + o_cnt1);
    int* cur1 = (int*)(ws + o_cur1);
    int* off1 = (int*)(ws + o_off1);
    int* ei0  = (int*)(ws + o_ei0);
    int* ei1  = (int*)(ws + o_ei1);

    hipMemsetAsync(flag, 0, 4, stream);
    hipMemsetAsync(cnt0, 0, N1v * 4, stream);
    hipMemsetAsync(cur0, 0, N1v * 4, stream);
    hipMemsetAsync(cnt1, 0, N2v * 4, stream);
    hipMemsetAsync(cur1, 0, N2v * 4, stream);

    // mask storage detection (reads 200000 bytes, valid for byte or int32 mask)
    k_detect<<<64, 256, 0, stream>>>((const unsigned int*)maskp, N1v, flag);

    // weight prep (split hi/lo, transposed)
    k_wsplit_hcat<<<32, 256, 0, stream>>>(w_pin, w_pout, WTph, WTpl, 128, 64);
    k_wsplit_vcat<<<96, 256, 0, stream>>>(w_self0, w_neigh0, WT0h, WT0l, 192, 384, 256);
    k_wsplit_vcat<<<128, 256, 0, stream>>>(w_self1, w_neigh1, WT1h, WT1l, 256, 512, 256);

    // prompt MLP fused with mask-select -> p_sel[N0,64]
    k_gemm_p<<<dim3(N0v / 64, 2), 256, 0, stream>>>(features, WTph, WTpl,
                                                    b_pin, b_pout, maskp, flag, psel);

    // CSR + aggregate layer 0 -> hcat0[N1,384] = [feat|psel|mean(feat)|mean(psel)]
    k_count<<<1024, 256, 0, stream>>>(dst0, E0v, cnt0);
    k_scan<<<1, 1024, 0, stream>>>(cnt0, off0, N1v);
    k_scatter<<<1024, 256, 0, stream>>>(src0, dst0, E0v, off0, cur0, ei0);
    k_agg0<<<(N1v + 3) / 4, 256, 0, stream>>>(features, psel, off0, ei0, hcat0);

    // h1 = relu(hcat0 @ [w_self0; w_neigh0] + b0)
    k_gemm<true><<<dim3((N1v + 63) / 64, 4), 256, 0, stream>>>(hcat0, WT0h, WT0l, b0,
                                                               h1, N1v, 384, 256);

    // CSR + aggregate layer 1 -> hcat1[N2,512]
    k_count<<<512, 256, 0, stream>>>(dst1, E1v, cnt1);
    k_scan<<<1, 1024, 0, stream>>>(cnt1, off1, N2v);
    k_scatter<<<512, 256, 0, stream>>>(src1, dst1, E1v, off1, cur1, ei1);
    k_agg1<<<(N2v + 3) / 4, 256, 0, stream>>>(h1, off1, ei1, hcat1);

    // h2 = hcat1 @ [w_self1; w_neigh1] + b1 (no relu)
    k_gemm<false><<<dim3((N2v + 63) / 64, 4), 256, 0, stream>>>(hcat1, WT1h, WT1l, b1,
                                                                h2, N2v, 512, 256);

    // logits
    k_cls<<<(N2v + 3) / 4, 256, 0, stream>>>(h2, w_cls, b_cls, out);
}